// Round 3
// baseline (45458.731 us; speedup 1.0000x reference)
//
#include <hip/hip_runtime.h>
#include <hip/hip_cooperative_groups.h>
#include <math.h>

namespace cg = cooperative_groups;

#define B64   64
#define TT    512
#define U400  400
#define G1600 1600
#define NBPL  80            // blocks per layer
#define UPB   5             // units per block (20 gate-columns)
#define NW    8             // waves per block
#define NTHR  512

// x [64][512][3] -> xT [512][3][64]
__global__ void xpose_x_k(const float* __restrict__ x, float* __restrict__ xT) {
  int idx = blockIdx.x * 256 + threadIdx.x;
  if (idx < B64 * TT * 3) {
    int d = idx % 3;
    int t = (idx / 3) % TT;
    int b = idx / (3 * TT);
    xT[(t * 3 + d) * B64 + b] = x[idx];
  }
}

// generic tiled transpose: in R x C -> out C x R
__global__ void transpose_k(const float* __restrict__ in, float* __restrict__ out,
                            int R, int C) {
  __shared__ float tile[32][33];
  int bx = blockIdx.x * 32, by = blockIdx.y * 32;
  int tx = threadIdx.x, ty = threadIdx.y; // block (32,8)
  #pragma unroll
  for (int i = ty; i < 32; i += 8) {
    int r = by + i, c = bx + tx;
    if (r < R && c < C) tile[i][tx] = in[(size_t)r * C + c];
  }
  __syncthreads();
  #pragma unroll
  for (int i = ty; i < 32; i += 8) {
    int r = bx + i, c = by + tx;
    if (r < C && c < R) out[(size_t)r * R + c] = tile[tx][i];
  }
}

struct CoopP {
  const float *xT0, *Wx0;
  const float *WxT1, *WxT2;
  const float *WhT0, *WhT1, *WhT2;
  const float *b0, *b1, *b2;
  const float *pi0, *pi1, *pi2;
  const float *pf0, *pf1, *pf2;
  const float *po0, *po1, *po2;
  float *h0r, *h1r;   // 8-slot rings [8][400][64]
  float *h2;          // full [512][400][64]
};

// Persistent cooperative LSTM scan, layer-wavefront over diagonals.
// grid = 240 blocks (80 per layer), block = 512 threads (8 waves).
// Block owns units [u0, u0+5): computes all 4 gates for them.
// Waves split the K dimension; weights via wave-uniform s_load streams.
__launch_bounds__(NTHR, 1)
__global__ void lstm_coop_k(CoopP p) {
  cg::grid_group grid = cg::this_grid();

  const int l    = blockIdx.x / NBPL;            // layer 0..2
  const int u0   = (blockIdx.x % NBPL) * UPB;    // first unit of this block
  const int lane = threadIdx.x & 63;
  const int kq   = __builtin_amdgcn_readfirstlane(threadIdx.x >> 6); // wave 0..7

  __shared__ float zs[NW][4 * UPB][B64];   // 40 KB partials

  // block-uniform per-layer pointers
  const float* WhT  = (l == 0) ? p.WhT0 : (l == 1 ? p.WhT1 : p.WhT2);
  const float* WxT  = (l == 1) ? p.WxT1 : p.WxT2;      // unused for l==0
  const float* bias = (l == 0) ? p.b0  : (l == 1 ? p.b1  : p.b2);
  const float* pi   = (l == 0) ? p.pi0 : (l == 1 ? p.pi1 : p.pi2);
  const float* pf   = (l == 0) ? p.pf0 : (l == 1 ? p.pf1 : p.pf2);
  const float* po   = (l == 0) ? p.po0 : (l == 1 ? p.po1 : p.po2);
  const float* prevb = (l == 1) ? p.h0r : p.h1r;       // layer l-1 output ring
  float* ownb = (l == 0) ? p.h0r : (l == 1 ? p.h1r : p.h2);
  const int ownmask = (l == 2) ? (TT - 1) : 7;

  // this wave's K-slice (wave-uniform)
  const float* wb; int k0, klenf, isH;
  if (l == 0)      { wb = WhT; k0 = kq * 50;        klenf = 50;  isH = 1; }
  else if (kq < 4) { wb = WxT; k0 = kq * 100;       klenf = 100; isH = 0; }
  else             { wb = WhT; k0 = (kq - 4) * 100; klenf = 100; isH = 1; }

  const float* wrow[4 * UPB];
  #pragma unroll
  for (int g = 0; g < 4; ++g)
    #pragma unroll
    for (int uu = 0; uu < UPB; ++uu)
      wrow[g * UPB + uu] = wb + (size_t)(g * U400 + u0 + uu) * U400 + k0;

  float creg = 0.f;   // cell state: thread tid<320 owns (unit u0+tid/64, batch tid%64)

  for (int d = 0; d < TT + 2; ++d) {
    const int t = d - l;
    const bool active = (t >= 0) && (t < TT);
    if (active) {
      float acc[4 * UPB];
      #pragma unroll
      for (int c = 0; c < 4 * UPB; ++c) acc[c] = 0.f;

      const int klen = (isH && t == 0) ? 0 : klenf;
      if (klen) {
        const float* aslab = isH
            ? ownb  + (size_t)((t - 1) & ownmask) * (U400 * B64) + (size_t)k0 * B64
            : prevb + (size_t)(t & 7)             * (U400 * B64) + (size_t)k0 * B64;
        #pragma unroll 4
        for (int kk = 0; kk < klen; ++kk) {
          float a = aslab[kk * B64 + lane];
          #pragma unroll
          for (int c = 0; c < 4 * UPB; ++c) acc[c] += a * wrow[c][kk];
        }
      }
      #pragma unroll
      for (int c = 0; c < 4 * UPB; ++c) zs[kq][c][lane] = acc[c];
    }
    __syncthreads();

    if (active && threadIdx.x < UPB * B64) {
      const int uu = threadIdx.x >> 6;
      const int b  = lane;
      const int u  = u0 + uu;
      float z0 = bias[0 * U400 + u], z1 = bias[1 * U400 + u];
      float z2 = bias[2 * U400 + u], z3 = bias[3 * U400 + u];
      #pragma unroll
      for (int w = 0; w < NW; ++w) {
        z0 += zs[w][0 * UPB + uu][b];
        z1 += zs[w][1 * UPB + uu][b];
        z2 += zs[w][2 * UPB + uu][b];
        z3 += zs[w][3 * UPB + uu][b];
      }
      if (l == 0) {
        #pragma unroll
        for (int dd = 0; dd < 3; ++dd) {
          float xv = p.xT0[(t * 3 + dd) * B64 + b];
          z0 += xv * p.Wx0[dd * G1600 + 0 * U400 + u];
          z1 += xv * p.Wx0[dd * G1600 + 1 * U400 + u];
          z2 += xv * p.Wx0[dd * G1600 + 2 * U400 + u];
          z3 += xv * p.Wx0[dd * G1600 + 3 * U400 + u];
        }
      }
      float cp = creg;
      float ig = 1.f / (1.f + expf(-(z0 + pi[u] * cp)));
      float fg = 1.f / (1.f + expf(-(z1 + pf[u] * cp)));
      float gg = tanhf(z2);
      float cn = fg * cp + ig * gg;
      float og = 1.f / (1.f + expf(-(z3 + po[u] * cn)));
      creg = cn;
      float h = og * tanhf(cn);
      ownb[(size_t)(t & ownmask) * (U400 * B64) + (size_t)u * B64 + b] = h;
    }
    __syncthreads();
    __threadfence();
    grid.sync();
  }
}

// out[b][t][f] = bd[f] + sum_u h2[t][u][b] * Wd[u][f]
__launch_bounds__(256)
__global__ void dense_k(const float* __restrict__ h2, const float* __restrict__ Wd,
                        const float* __restrict__ bd, float* __restrict__ out) {
  int wid  = blockIdx.x * 4 + (threadIdx.x >> 6);
  int lane = threadIdx.x & 63;
  int t = wid / 3, f = wid - t * 3;
  if (t >= TT) return;
  float acc = bd[f];
  const float* hrow = h2 + (size_t)t * U400 * B64 + lane;
  #pragma unroll 4
  for (int u = 0; u < U400; ++u) acc += hrow[(size_t)u * B64] * Wd[u * 3 + f];
  out[((size_t)lane * TT + t) * 3 + f] = acc;
}

extern "C" void kernel_launch(void* const* d_in, const int* in_sizes, int n_in,
                              void* d_out, int out_size, void* d_ws, size_t ws_size,
                              hipStream_t stream) {
  const float* x   = (const float*)d_in[0];
  const float* Wx0 = (const float*)d_in[1];
  const float* Wh0 = (const float*)d_in[2];
  const float* pi0 = (const float*)d_in[3];
  const float* pf0 = (const float*)d_in[4];
  const float* po0 = (const float*)d_in[5];
  const float* b0  = (const float*)d_in[6];
  const float* Wx1 = (const float*)d_in[7];
  const float* Wh1 = (const float*)d_in[8];
  const float* pi1 = (const float*)d_in[9];
  const float* pf1 = (const float*)d_in[10];
  const float* po1 = (const float*)d_in[11];
  const float* b1  = (const float*)d_in[12];
  const float* Wx2 = (const float*)d_in[13];
  const float* Wh2 = (const float*)d_in[14];
  const float* pi2 = (const float*)d_in[15];
  const float* pf2 = (const float*)d_in[16];
  const float* po2 = (const float*)d_in[17];
  const float* b2  = (const float*)d_in[18];
  const float* Wd  = (const float*)d_in[19];
  const float* bd  = (const float*)d_in[20];

  float* ws   = (float*)d_ws;
  float* xT0  = ws;                  // 98304
  float* WhT0 = xT0  + 98304;        // 640000 each
  float* WhT1 = WhT0 + 640000;
  float* WhT2 = WhT1 + 640000;
  float* WxT1 = WhT2 + 640000;
  float* WxT2 = WxT1 + 640000;
  float* h0r  = WxT2 + 640000;       // 8*400*64 = 204800
  float* h1r  = h0r  + 204800;       // 204800
  float* h2   = h1r  + 204800;       // 13107200

  hipLaunchKernelGGL(xpose_x_k, dim3(384), dim3(256), 0, stream, x, xT0);

  dim3 tb(32, 8);
  dim3 tg((G1600 + 31) / 32, (U400 + 31) / 32);
  hipLaunchKernelGGL(transpose_k, tg, tb, 0, stream, Wh0, WhT0, U400, G1600);
  hipLaunchKernelGGL(transpose_k, tg, tb, 0, stream, Wh1, WhT1, U400, G1600);
  hipLaunchKernelGGL(transpose_k, tg, tb, 0, stream, Wh2, WhT2, U400, G1600);
  hipLaunchKernelGGL(transpose_k, tg, tb, 0, stream, Wx1, WxT1, U400, G1600);
  hipLaunchKernelGGL(transpose_k, tg, tb, 0, stream, Wx2, WxT2, U400, G1600);

  CoopP hp;
  hp.xT0 = xT0;  hp.Wx0 = Wx0;
  hp.WxT1 = WxT1; hp.WxT2 = WxT2;
  hp.WhT0 = WhT0; hp.WhT1 = WhT1; hp.WhT2 = WhT2;
  hp.b0 = b0; hp.b1 = b1; hp.b2 = b2;
  hp.pi0 = pi0; hp.pi1 = pi1; hp.pi2 = pi2;
  hp.pf0 = pf0; hp.pf1 = pf1; hp.pf2 = pf2;
  hp.po0 = po0; hp.po1 = po1; hp.po2 = po2;
  hp.h0r = h0r; hp.h1r = h1r; hp.h2 = h2;

  void* args[] = { &hp };
  hipLaunchCooperativeKernel((void*)lstm_coop_k, dim3(3 * NBPL), dim3(NTHR),
                             args, 0, stream);

  hipLaunchKernelGGL(dense_k, dim3(384), dim3(256), 0, stream, h2, Wd, bd,
                     (float*)d_out);
}

// Round 4
// 22024.927 us; speedup vs baseline: 2.0640x; 2.0640x over previous
//
#include <hip/hip_runtime.h>
#include <math.h>

#define B64   64
#define TT    512
#define U400  400
#define G1600 1600
#define NBPL  80            // blocks per layer
#define UPB   5             // units per block (20 gate-columns)
#define NW    8             // waves per block
#define NTHR  512
#define NBLK  (3 * NBPL)

// x [64][512][3] -> xT [512][3][64]
__global__ void xpose_x_k(const float* __restrict__ x, float* __restrict__ xT) {
  int idx = blockIdx.x * 256 + threadIdx.x;
  if (idx < B64 * TT * 3) {
    int d = idx % 3;
    int t = (idx / 3) % TT;
    int b = idx / (3 * TT);
    xT[(t * 3 + d) * B64 + b] = x[idx];
  }
}

// generic tiled transpose: in R x C -> out C x R
__global__ void transpose_k(const float* __restrict__ in, float* __restrict__ out,
                            int R, int C) {
  __shared__ float tile[32][33];
  int bx = blockIdx.x * 32, by = blockIdx.y * 32;
  int tx = threadIdx.x, ty = threadIdx.y; // block (32,8)
  #pragma unroll
  for (int i = ty; i < 32; i += 8) {
    int r = by + i, c = bx + tx;
    if (r < R && c < C) tile[i][tx] = in[(size_t)r * C + c];
  }
  __syncthreads();
  #pragma unroll
  for (int i = ty; i < 32; i += 8) {
    int r = bx + i, c = by + tx;
    if (r < C && c < R) out[(size_t)r * R + c] = tile[tx][i];
  }
}

struct CoopP {
  const float *xT0, *Wx0;
  const float *WxT1, *WxT2;
  const float *WhT0, *WhT1, *WhT2;
  const float *b0, *b1, *b2;
  const float *pi0, *pi1, *pi2;
  const float *pf0, *pf1, *pf2;
  const float *po0, *po1, *po2;
  float *h0r, *h1r;   // 8-slot rings [8][400][64]
  float *h2;          // full [512][400][64]
  unsigned *bctr, *bgen;  // grid barrier state (memset to 0 each launch)
};

// Persistent LSTM scan, layer-wavefront over diagonals, custom grid barrier.
// grid = 240 blocks (80 per layer), block = 512 threads (8 waves).
// Block owns units [u0, u0+5); waves split K; cell state in registers.
__launch_bounds__(NTHR, 1)
__global__ void lstm_coop_k(CoopP p) {
  const int l    = blockIdx.x / NBPL;            // layer 0..2
  const int u0   = (blockIdx.x % NBPL) * UPB;    // first unit of this block
  const int lane = threadIdx.x & 63;
  const int kq   = __builtin_amdgcn_readfirstlane(threadIdx.x >> 6); // wave 0..7

  __shared__ float zs[NW][4 * UPB][B64];   // 40 KB partials

  // block-uniform per-layer pointers
  const float* WhT  = (l == 0) ? p.WhT0 : (l == 1 ? p.WhT1 : p.WhT2);
  const float* WxT  = (l == 1) ? p.WxT1 : p.WxT2;      // unused for l==0
  const float* bias = (l == 0) ? p.b0  : (l == 1 ? p.b1  : p.b2);
  const float* pi   = (l == 0) ? p.pi0 : (l == 1 ? p.pi1 : p.pi2);
  const float* pf   = (l == 0) ? p.pf0 : (l == 1 ? p.pf1 : p.pf2);
  const float* po   = (l == 0) ? p.po0 : (l == 1 ? p.po1 : p.po2);
  const float* prevb = (l == 1) ? p.h0r : p.h1r;       // layer l-1 output ring
  float* ownb = (l == 0) ? p.h0r : (l == 1 ? p.h1r : p.h2);
  const int ownmask = (l == 2) ? (TT - 1) : 7;

  // this wave's K-slice (wave-uniform)
  const float* wb; int k0, klenf, isH;
  if (l == 0)      { wb = WhT; k0 = kq * 50;        klenf = 50;  isH = 1; }
  else if (kq < 4) { wb = WxT; k0 = kq * 100;       klenf = 100; isH = 0; }
  else             { wb = WhT; k0 = (kq - 4) * 100; klenf = 100; isH = 1; }

  const float* wrow[4 * UPB];
  #pragma unroll
  for (int g = 0; g < 4; ++g)
    #pragma unroll
    for (int uu = 0; uu < UPB; ++uu)
      wrow[g * UPB + uu] = wb + (size_t)(g * U400 + u0 + uu) * U400 + k0;

  float creg = 0.f;   // cell state: thread tid<320 owns (unit u0+tid/64, batch tid%64)

  for (int d = 0; d < TT + 2; ++d) {
    const int t = d - l;
    const bool active = (t >= 0) && (t < TT);
    if (active) {
      float acc[4 * UPB];
      #pragma unroll
      for (int c = 0; c < 4 * UPB; ++c) acc[c] = 0.f;

      const int klen = (isH && t == 0) ? 0 : klenf;
      if (klen) {
        const float* aslab = isH
            ? ownb  + (size_t)((t - 1) & ownmask) * (U400 * B64) + (size_t)k0 * B64
            : prevb + (size_t)(t & 7)             * (U400 * B64) + (size_t)k0 * B64;
        #pragma unroll 4
        for (int kk = 0; kk < klen; ++kk) {
          float a = aslab[kk * B64 + lane];
          #pragma unroll
          for (int c = 0; c < 4 * UPB; ++c) acc[c] += a * wrow[c][kk];
        }
      }
      #pragma unroll
      for (int c = 0; c < 4 * UPB; ++c) zs[kq][c][lane] = acc[c];
    }
    __syncthreads();

    if (active && threadIdx.x < UPB * B64) {
      const int uu = threadIdx.x >> 6;
      const int b  = lane;
      const int u  = u0 + uu;
      float z0 = bias[0 * U400 + u], z1 = bias[1 * U400 + u];
      float z2 = bias[2 * U400 + u], z3 = bias[3 * U400 + u];
      #pragma unroll
      for (int w = 0; w < NW; ++w) {
        z0 += zs[w][0 * UPB + uu][b];
        z1 += zs[w][1 * UPB + uu][b];
        z2 += zs[w][2 * UPB + uu][b];
        z3 += zs[w][3 * UPB + uu][b];
      }
      if (l == 0) {
        #pragma unroll
        for (int dd = 0; dd < 3; ++dd) {
          float xv = p.xT0[(t * 3 + dd) * B64 + b];
          z0 += xv * p.Wx0[dd * G1600 + 0 * U400 + u];
          z1 += xv * p.Wx0[dd * G1600 + 1 * U400 + u];
          z2 += xv * p.Wx0[dd * G1600 + 2 * U400 + u];
          z3 += xv * p.Wx0[dd * G1600 + 3 * U400 + u];
        }
      }
      float cp = creg;
      float ig = 1.f / (1.f + expf(-(z0 + pi[u] * cp)));
      float fg = 1.f / (1.f + expf(-(z1 + pf[u] * cp)));
      float gg = tanhf(z2);
      float cn = fg * cp + ig * gg;
      float og = 1.f / (1.f + expf(-(z3 + po[u] * cn)));
      creg = cn;
      float h = og * tanhf(cn);
      ownb[(size_t)(t & ownmask) * (U400 * B64) + (size_t)u * B64 + b] = h;
    }

    // ---- custom grid barrier (sense-free, monotone generation) ----
    __syncthreads();   // drains vmcnt(0) for all waves -> h stores in L2
    if (threadIdx.x == 0) {
      __builtin_amdgcn_fence(__ATOMIC_RELEASE, "agent");   // wb dirty L2 lines
      unsigned old = __hip_atomic_fetch_add(p.bctr, 1u, __ATOMIC_RELAXED,
                                            __HIP_MEMORY_SCOPE_AGENT);
      unsigned tgt = (unsigned)(d + 1);
      if (old == (unsigned)(NBLK - 1)) {
        __hip_atomic_store(p.bctr, 0u, __ATOMIC_RELAXED, __HIP_MEMORY_SCOPE_AGENT);
        __hip_atomic_store(p.bgen, tgt, __ATOMIC_RELEASE, __HIP_MEMORY_SCOPE_AGENT);
      } else {
        while ((int)(__hip_atomic_load(p.bgen, __ATOMIC_RELAXED,
                                       __HIP_MEMORY_SCOPE_AGENT) - tgt) < 0)
          __builtin_amdgcn_s_sleep(8);
      }
      __builtin_amdgcn_fence(__ATOMIC_ACQUIRE, "agent");   // inv L1+L2
    }
    __syncthreads();
  }
}

// out[b][t][f] = bd[f] + sum_u h2[t][u][b] * Wd[u][f]
__launch_bounds__(256)
__global__ void dense_k(const float* __restrict__ h2, const float* __restrict__ Wd,
                        const float* __restrict__ bd, float* __restrict__ out) {
  int wid  = blockIdx.x * 4 + (threadIdx.x >> 6);
  int lane = threadIdx.x & 63;
  int t = wid / 3, f = wid - t * 3;
  if (t >= TT) return;
  float acc = bd[f];
  const float* hrow = h2 + (size_t)t * U400 * B64 + lane;
  #pragma unroll 4
  for (int u = 0; u < U400; ++u) acc += hrow[(size_t)u * B64] * Wd[u * 3 + f];
  out[((size_t)lane * TT + t) * 3 + f] = acc;
}

extern "C" void kernel_launch(void* const* d_in, const int* in_sizes, int n_in,
                              void* d_out, int out_size, void* d_ws, size_t ws_size,
                              hipStream_t stream) {
  const float* x   = (const float*)d_in[0];
  const float* Wx0 = (const float*)d_in[1];
  const float* Wh0 = (const float*)d_in[2];
  const float* pi0 = (const float*)d_in[3];
  const float* pf0 = (const float*)d_in[4];
  const float* po0 = (const float*)d_in[5];
  const float* b0  = (const float*)d_in[6];
  const float* Wx1 = (const float*)d_in[7];
  const float* Wh1 = (const float*)d_in[8];
  const float* pi1 = (const float*)d_in[9];
  const float* pf1 = (const float*)d_in[10];
  const float* po1 = (const float*)d_in[11];
  const float* b1  = (const float*)d_in[12];
  const float* Wx2 = (const float*)d_in[13];
  const float* Wh2 = (const float*)d_in[14];
  const float* pi2 = (const float*)d_in[15];
  const float* pf2 = (const float*)d_in[16];
  const float* po2 = (const float*)d_in[17];
  const float* b2  = (const float*)d_in[18];
  const float* Wd  = (const float*)d_in[19];
  const float* bd  = (const float*)d_in[20];

  float* ws   = (float*)d_ws;
  float* xT0  = ws;                  // 98304
  float* WhT0 = xT0  + 98304;        // 640000 each
  float* WhT1 = WhT0 + 640000;
  float* WhT2 = WhT1 + 640000;
  float* WxT1 = WhT2 + 640000;
  float* WxT2 = WxT1 + 640000;
  float* h0r  = WxT2 + 640000;       // 8*400*64 = 204800
  float* h1r  = h0r  + 204800;       // 204800
  float* h2   = h1r  + 204800;       // 13107200
  unsigned* bar = (unsigned*)(h2 + 13107200);  // [0]=ctr [1]=gen

  hipMemsetAsync(bar, 0, 2 * sizeof(unsigned), stream);

  hipLaunchKernelGGL(xpose_x_k, dim3(384), dim3(256), 0, stream, x, xT0);

  dim3 tb(32, 8);
  dim3 tg((G1600 + 31) / 32, (U400 + 31) / 32);
  hipLaunchKernelGGL(transpose_k, tg, tb, 0, stream, Wh0, WhT0, U400, G1600);
  hipLaunchKernelGGL(transpose_k, tg, tb, 0, stream, Wh1, WhT1, U400, G1600);
  hipLaunchKernelGGL(transpose_k, tg, tb, 0, stream, Wh2, WhT2, U400, G1600);
  hipLaunchKernelGGL(transpose_k, tg, tb, 0, stream, Wx1, WxT1, U400, G1600);
  hipLaunchKernelGGL(transpose_k, tg, tb, 0, stream, Wx2, WxT2, U400, G1600);

  CoopP hp;
  hp.xT0 = xT0;  hp.Wx0 = Wx0;
  hp.WxT1 = WxT1; hp.WxT2 = WxT2;
  hp.WhT0 = WhT0; hp.WhT1 = WhT1; hp.WhT2 = WhT2;
  hp.b0 = b0; hp.b1 = b1; hp.b2 = b2;
  hp.pi0 = pi0; hp.pi1 = pi1; hp.pi2 = pi2;
  hp.pf0 = pf0; hp.pf1 = pf1; hp.pf2 = pf2;
  hp.po0 = po0; hp.po1 = po1; hp.po2 = po2;
  hp.h0r = h0r; hp.h1r = h1r; hp.h2 = h2;
  hp.bctr = bar; hp.bgen = bar + 1;

  void* args[] = { &hp };
  hipLaunchCooperativeKernel((void*)lstm_coop_k, dim3(NBLK), dim3(NTHR),
                             args, 0, stream);

  hipLaunchKernelGGL(dense_k, dim3(384), dim3(256), 0, stream, h2, Wd, bd,
                     (float*)d_out);
}

// Round 5
// 18543.700 us; speedup vs baseline: 2.4514x; 1.1877x over previous
//
#include <hip/hip_runtime.h>
#include <math.h>

#define B64   64
#define TT    512
#define U400  400
#define G1600 1600
#define NBPL  80            // blocks per layer
#define UPB   5             // units per block (20 gate-columns)
#define NW    8             // waves per block
#define NTHR  512
#define NBLK  (3 * NBPL)

// ---- device-coherent (sc1) access helpers: bypass L1/L2, served at L3 ----
__device__ __forceinline__ float ldg_c(const float* p) {
  return __hip_atomic_load(p, __ATOMIC_RELAXED, __HIP_MEMORY_SCOPE_AGENT);
}
__device__ __forceinline__ void stg_c(float* p, float v) {
  __hip_atomic_store(p, v, __ATOMIC_RELAXED, __HIP_MEMORY_SCOPE_AGENT);
}

// x [64][512][3] -> xT [512][3][64]
__global__ void xpose_x_k(const float* __restrict__ x, float* __restrict__ xT) {
  int idx = blockIdx.x * 256 + threadIdx.x;
  if (idx < B64 * TT * 3) {
    int d = idx % 3;
    int t = (idx / 3) % TT;
    int b = idx / (3 * TT);
    xT[(t * 3 + d) * B64 + b] = x[idx];
  }
}

// generic tiled transpose: in R x C -> out C x R
__global__ void transpose_k(const float* __restrict__ in, float* __restrict__ out,
                            int R, int C) {
  __shared__ float tile[32][33];
  int bx = blockIdx.x * 32, by = blockIdx.y * 32;
  int tx = threadIdx.x, ty = threadIdx.y; // block (32,8)
  #pragma unroll
  for (int i = ty; i < 32; i += 8) {
    int r = by + i, c = bx + tx;
    if (r < R && c < C) tile[i][tx] = in[(size_t)r * C + c];
  }
  __syncthreads();
  #pragma unroll
  for (int i = ty; i < 32; i += 8) {
    int r = bx + i, c = by + tx;
    if (r < C && c < R) out[(size_t)r * R + c] = tile[tx][i];
  }
}

struct ScanP {
  const float *xT0, *Wx0;
  const float *WxT1, *WxT2;
  const float *WhT0, *WhT1, *WhT2;
  const float *b0, *b1, *b2;
  const float *pi0, *pi1, *pi2;
  const float *pf0, *pf1, *pf2;
  const float *po0, *po1, *po2;
  float *h0r, *h1r;   // 8-slot rings [8][400][64]
  float *h2;          // full [512][400][64]
  unsigned *sync;     // [0..2] cnt per layer, [3..5] monotone arrive accumulators
};

// Persistent LSTM scan. Per-layer producer/consumer sync, no fences.
// grid = 240 blocks (80 per layer), block = 512 threads (8 waves).
// Each layer runs its own t-loop; waits: own peers done t-1, upstream done t,
// downstream >= t-7 (ring slot free). Weights stay L2-cached (never fenced);
// cross-block h data + counters go through agent-scope (sc1) atomics.
__launch_bounds__(NTHR, 1)
__global__ void lstm_scan_k(ScanP p) {
  const int l    = blockIdx.x / NBPL;            // layer 0..2
  const int u0   = (blockIdx.x % NBPL) * UPB;    // first unit of this block
  const int lane = threadIdx.x & 63;
  const int kq   = __builtin_amdgcn_readfirstlane(threadIdx.x >> 6); // wave 0..7

  __shared__ float zs[NW][4 * UPB][B64];   // 40 KB partials

  const float* WhT  = (l == 0) ? p.WhT0 : (l == 1 ? p.WhT1 : p.WhT2);
  const float* WxT  = (l == 1) ? p.WxT1 : p.WxT2;      // unused for l==0
  const float* bias = (l == 0) ? p.b0  : (l == 1 ? p.b1  : p.b2);
  const float* pi   = (l == 0) ? p.pi0 : (l == 1 ? p.pi1 : p.pi2);
  const float* pf   = (l == 0) ? p.pf0 : (l == 1 ? p.pf1 : p.pf2);
  const float* po   = (l == 0) ? p.po0 : (l == 1 ? p.po1 : p.po2);
  const float* prevb = (l == 1) ? p.h0r : p.h1r;       // layer l-1 output ring
  float* ownb = (l == 0) ? p.h0r : (l == 1 ? p.h1r : p.h2);
  const int ownmask = (l == 2) ? (TT - 1) : 7;

  unsigned* cnt = p.sync;        // [3]
  unsigned* acc_ = p.sync + 3;   // [3] monotone arrive accumulators

  // this wave's K-slice (wave-uniform)
  const float* wb; int k0, klenf, isH;
  if (l == 0)      { wb = WhT; k0 = kq * 50;        klenf = 50;  isH = 1; }
  else if (kq < 4) { wb = WxT; k0 = kq * 100;       klenf = 100; isH = 0; }
  else             { wb = WhT; k0 = (kq - 4) * 100; klenf = 100; isH = 1; }

  const float* wrow[4 * UPB];
  #pragma unroll
  for (int g = 0; g < 4; ++g)
    #pragma unroll
    for (int uu = 0; uu < UPB; ++uu)
      wrow[g * UPB + uu] = wb + (size_t)(g * U400 + u0 + uu) * U400 + k0;

  float creg = 0.f;

  for (int t = 0; t < TT; ++t) {
    // ---- wait phase (thread 0 spins on device-coherent counters) ----
    if (threadIdx.x == 0) {
      while ((int)__hip_atomic_load(&cnt[l], __ATOMIC_RELAXED,
                                    __HIP_MEMORY_SCOPE_AGENT) < t)
        __builtin_amdgcn_s_sleep(1);
      if (l > 0)
        while ((int)__hip_atomic_load(&cnt[l - 1], __ATOMIC_RELAXED,
                                      __HIP_MEMORY_SCOPE_AGENT) < t + 1)
          __builtin_amdgcn_s_sleep(1);
      if (l < 2)
        while ((int)__hip_atomic_load(&cnt[l + 1], __ATOMIC_RELAXED,
                                      __HIP_MEMORY_SCOPE_AGENT) < t - 7)
          __builtin_amdgcn_s_sleep(1);
    }
    __syncthreads();

    // ---- GEMM phase ----
    {
      float acc[4 * UPB];
      #pragma unroll
      for (int c = 0; c < 4 * UPB; ++c) acc[c] = 0.f;

      const int klen = (isH && t == 0) ? 0 : klenf;
      if (klen) {
        const float* aslab = isH
            ? ownb  + (size_t)((t - 1) & ownmask) * (U400 * B64) + (size_t)k0 * B64
            : prevb + (size_t)(t & 7)             * (U400 * B64) + (size_t)k0 * B64;
        #pragma unroll 4
        for (int kk = 0; kk < klen; ++kk) {
          float a = ldg_c(&aslab[kk * B64 + lane]);
          #pragma unroll
          for (int c = 0; c < 4 * UPB; ++c) acc[c] += a * wrow[c][kk];
        }
      }
      #pragma unroll
      for (int c = 0; c < 4 * UPB; ++c) zs[kq][c][lane] = acc[c];
    }
    __syncthreads();

    // ---- pointwise phase ----
    if (threadIdx.x < UPB * B64) {
      const int uu = threadIdx.x >> 6;
      const int b  = lane;
      const int u  = u0 + uu;
      float z0 = bias[0 * U400 + u], z1 = bias[1 * U400 + u];
      float z2 = bias[2 * U400 + u], z3 = bias[3 * U400 + u];
      #pragma unroll
      for (int w = 0; w < NW; ++w) {
        z0 += zs[w][0 * UPB + uu][b];
        z1 += zs[w][1 * UPB + uu][b];
        z2 += zs[w][2 * UPB + uu][b];
        z3 += zs[w][3 * UPB + uu][b];
      }
      if (l == 0) {
        #pragma unroll
        for (int dd = 0; dd < 3; ++dd) {
          float xv = p.xT0[(t * 3 + dd) * B64 + b];
          z0 += xv * p.Wx0[dd * G1600 + 0 * U400 + u];
          z1 += xv * p.Wx0[dd * G1600 + 1 * U400 + u];
          z2 += xv * p.Wx0[dd * G1600 + 2 * U400 + u];
          z3 += xv * p.Wx0[dd * G1600 + 3 * U400 + u];
        }
      }
      float cp = creg;
      float ig = 1.f / (1.f + expf(-(z0 + pi[u] * cp)));
      float fg = 1.f / (1.f + expf(-(z1 + pf[u] * cp)));
      float gg = tanhf(z2);
      float cn = fg * cp + ig * gg;
      float og = 1.f / (1.f + expf(-(z3 + po[u] * cn)));
      creg = cn;
      float h = og * tanhf(cn);
      stg_c(&ownb[(size_t)(t & ownmask) * (U400 * B64) + (size_t)u * B64 + b], h);
    }

    // drain: every wave's s_waitcnt vmcnt(0) before s_barrier ensures all sc1
    // h-stores are acked at the coherence point before the arrive RMW below.
    __syncthreads();

    // ---- arrive (monotone accumulator; no resets -> no ordering hazard) ----
    if (threadIdx.x == 0) {
      unsigned old = __hip_atomic_fetch_add(&acc_[l], 1u, __ATOMIC_RELAXED,
                                            __HIP_MEMORY_SCOPE_AGENT);
      if (old == (unsigned)((t + 1) * NBPL - 1))
        __hip_atomic_store(&cnt[l], (unsigned)(t + 1), __ATOMIC_RELAXED,
                           __HIP_MEMORY_SCOPE_AGENT);
    }
  }
}

// out[b][t][f] = bd[f] + sum_u h2[t][u][b] * Wd[u][f]
__launch_bounds__(256)
__global__ void dense_k(const float* __restrict__ h2, const float* __restrict__ Wd,
                        const float* __restrict__ bd, float* __restrict__ out) {
  int wid  = blockIdx.x * 4 + (threadIdx.x >> 6);
  int lane = threadIdx.x & 63;
  int t = wid / 3, f = wid - t * 3;
  if (t >= TT) return;
  float acc = bd[f];
  const float* hrow = h2 + (size_t)t * U400 * B64 + lane;
  #pragma unroll 4
  for (int u = 0; u < U400; ++u) acc += hrow[(size_t)u * B64] * Wd[u * 3 + f];
  out[((size_t)lane * TT + t) * 3 + f] = acc;
}

extern "C" void kernel_launch(void* const* d_in, const int* in_sizes, int n_in,
                              void* d_out, int out_size, void* d_ws, size_t ws_size,
                              hipStream_t stream) {
  const float* x   = (const float*)d_in[0];
  const float* Wx0 = (const float*)d_in[1];
  const float* Wh0 = (const float*)d_in[2];
  const float* pi0 = (const float*)d_in[3];
  const float* pf0 = (const float*)d_in[4];
  const float* po0 = (const float*)d_in[5];
  const float* b0  = (const float*)d_in[6];
  const float* Wx1 = (const float*)d_in[7];
  const float* Wh1 = (const float*)d_in[8];
  const float* pi1 = (const float*)d_in[9];
  const float* pf1 = (const float*)d_in[10];
  const float* po1 = (const float*)d_in[11];
  const float* b1  = (const float*)d_in[12];
  const float* Wx2 = (const float*)d_in[13];
  const float* Wh2 = (const float*)d_in[14];
  const float* pi2 = (const float*)d_in[15];
  const float* pf2 = (const float*)d_in[16];
  const float* po2 = (const float*)d_in[17];
  const float* b2  = (const float*)d_in[18];
  const float* Wd  = (const float*)d_in[19];
  const float* bd  = (const float*)d_in[20];

  float* ws   = (float*)d_ws;
  float* xT0  = ws;                  // 98304
  float* WhT0 = xT0  + 98304;        // 640000 each
  float* WhT1 = WhT0 + 640000;
  float* WhT2 = WhT1 + 640000;
  float* WxT1 = WhT2 + 640000;
  float* WxT2 = WxT1 + 640000;
  float* h0r  = WxT2 + 640000;       // 8*400*64 = 204800
  float* h1r  = h0r  + 204800;       // 204800
  float* h2   = h1r  + 204800;       // 13107200
  unsigned* syn = (unsigned*)(h2 + 13107200);  // 6 counters

  hipMemsetAsync(syn, 0, 64, stream);

  hipLaunchKernelGGL(xpose_x_k, dim3(384), dim3(256), 0, stream, x, xT0);

  dim3 tb(32, 8);
  dim3 tg((G1600 + 31) / 32, (U400 + 31) / 32);
  hipLaunchKernelGGL(transpose_k, tg, tb, 0, stream, Wh0, WhT0, U400, G1600);
  hipLaunchKernelGGL(transpose_k, tg, tb, 0, stream, Wh1, WhT1, U400, G1600);
  hipLaunchKernelGGL(transpose_k, tg, tb, 0, stream, Wh2, WhT2, U400, G1600);
  hipLaunchKernelGGL(transpose_k, tg, tb, 0, stream, Wx1, WxT1, U400, G1600);
  hipLaunchKernelGGL(transpose_k, tg, tb, 0, stream, Wx2, WxT2, U400, G1600);

  ScanP hp;
  hp.xT0 = xT0;  hp.Wx0 = Wx0;
  hp.WxT1 = WxT1; hp.WxT2 = WxT2;
  hp.WhT0 = WhT0; hp.WhT1 = WhT1; hp.WhT2 = WhT2;
  hp.b0 = b0; hp.b1 = b1; hp.b2 = b2;
  hp.pi0 = pi0; hp.pi1 = pi1; hp.pi2 = pi2;
  hp.pf0 = pf0; hp.pf1 = pf1; hp.pf2 = pf2;
  hp.po0 = po0; hp.po1 = po1; hp.po2 = po2;
  hp.h0r = h0r; hp.h1r = h1r; hp.h2 = h2;
  hp.sync = syn;

  // cooperative launch only for the co-residency guarantee (no grid.sync used)
  void* args[] = { &hp };
  hipLaunchCooperativeKernel((void*)lstm_scan_k, dim3(NBLK), dim3(NTHR),
                             args, 0, stream);

  hipLaunchKernelGGL(dense_k, dim3(384), dim3(256), 0, stream, h2, Wd, bd,
                     (float*)d_out);
}